// Round 1
// baseline (1521.093 us; speedup 1.0000x reference)
//
#include <hip/hip_runtime.h>
#include <cstddef>

// Problem constants
static constexpr int Bc  = 4;
static constexpr int Cc  = 512;
static constexpr int Nc  = 2048;
static constexpr int Hc  = 8;
static constexpr int DKc = 64;
static constexpr int O3c = 1536;       // 3*H*DK
static constexpr float SCALE = 0.125f; // DK^-0.5

// ---------------------------------------------------------------------------
// Kernel 1: qkv projection.  qkv[b,n,o] = sum_c x[b,c,n] * Wp[o,c] + bp[o]
// scattered into q/k/v [b,h,n,d].  grid (Nc/64, O3c/64, Bc), block 256.
// Each 64-wide o-tile maps to exactly one (head, field): m=o0/64, h=m/3, f=m%3.
// ---------------------------------------------------------------------------
__global__ __launch_bounds__(256) void qkv_kernel(
    const float* __restrict__ x, const float* __restrict__ Wp,
    const float* __restrict__ bp,
    float* __restrict__ qws, float* __restrict__ kws, float* __restrict__ vws)
{
    __shared__ float As[16][64];   // [k][n]
    __shared__ float Bs[16][68];   // [k][o], padded
    const int tid = threadIdx.x;
    const int b  = blockIdx.z;
    const int n0 = blockIdx.x * 64;
    const int o0 = blockIdx.y * 64;
    const int tn = tid & 15;       // n quad
    const int to = tid >> 4;       // o quad
    float acc[4][4] = {};
    const float* xb = x + (size_t)b * Cc * Nc;

    for (int kc = 0; kc < Cc; kc += 16) {
#pragma unroll
        for (int it = 0; it < 4; ++it) {
            int e = it * 256 + tid;
            int kk = e >> 6, nn = e & 63;
            As[kk][nn] = xb[(size_t)(kc + kk) * Nc + n0 + nn];
        }
#pragma unroll
        for (int it = 0; it < 4; ++it) {
            int e = it * 256 + tid;
            int oo = e >> 4, kk = e & 15;
            Bs[kk][oo] = Wp[(size_t)(o0 + oo) * Cc + kc + kk];
        }
        __syncthreads();
#pragma unroll
        for (int kk = 0; kk < 16; ++kk) {
            float4 a  = *(const float4*)&As[kk][tn * 4];
            float4 bv = *(const float4*)&Bs[kk][to * 4];
            float av[4] = {a.x, a.y, a.z, a.w};
            float bw[4] = {bv.x, bv.y, bv.z, bv.w};
#pragma unroll
            for (int r = 0; r < 4; ++r)
#pragma unroll
                for (int s = 0; s < 4; ++s)
                    acc[r][s] += av[r] * bw[s];
        }
        __syncthreads();
    }

    const int m = o0 >> 6;      // 0..23
    const int h = m / 3;
    const int f = m % 3;
    float* dst = (f == 0 ? qws : (f == 1 ? kws : vws));
    dst += ((size_t)(b * Hc + h) * Nc) * DKc;
    float b0 = bp[o0 + to * 4 + 0];
    float b1 = bp[o0 + to * 4 + 1];
    float b2 = bp[o0 + to * 4 + 2];
    float b3 = bp[o0 + to * 4 + 3];
#pragma unroll
    for (int r = 0; r < 4; ++r) {
        int n = n0 + tn * 4 + r;
        float4 v;
        v.x = acc[r][0] + b0;
        v.y = acc[r][1] + b1;
        v.z = acc[r][2] + b2;
        v.w = acc[r][3] + b3;
        *(float4*)&dst[(size_t)n * DKc + to * 4] = v;
    }
}

// ---------------------------------------------------------------------------
// Kernel 2: column stats. coef[bh,j] = 1 / sum_i exp(scale * q_i . k_j)
// grid (Nc/64 j-tiles, Bc*Hc), block 256.
// Thread (tis=tid>>4, tjs=tid&15): rows i = tis*4+r, cols j = s*16+tjs.
// ---------------------------------------------------------------------------
__global__ __launch_bounds__(256) void stats_kernel(
    const float* __restrict__ qws, const float* __restrict__ kws,
    float* __restrict__ coef)
{
    __shared__ float Ks[64][68];
    __shared__ float Qs[64][68];
    __shared__ float red[16][64];
    const int tid = threadIdx.x;
    const int bh = blockIdx.y;
    const int j0 = blockIdx.x * 64;
    const int tjs = tid & 15;
    const int tis = tid >> 4;

    const float* kbase = kws + ((size_t)bh * Nc + j0) * DKc;
#pragma unroll
    for (int it = 0; it < 4; ++it) {
        int e = it * 256 + tid;
        int row = e >> 4, c4 = e & 15;
        *(float4*)&Ks[row][c4 * 4] = *(const float4*)&kbase[(size_t)row * DKc + c4 * 4];
    }

    float lsum[4] = {0.f, 0.f, 0.f, 0.f};
    const float* qbase = qws + (size_t)bh * Nc * DKc;

    for (int i0 = 0; i0 < Nc; i0 += 64) {
#pragma unroll
        for (int it = 0; it < 4; ++it) {
            int e = it * 256 + tid;
            int row = e >> 4, c4 = e & 15;
            *(float4*)&Qs[row][c4 * 4] =
                *(const float4*)&qbase[(size_t)(i0 + row) * DKc + c4 * 4];
        }
        __syncthreads();

        float sacc[4][4] = {};
#pragma unroll
        for (int d4 = 0; d4 < 16; ++d4) {
            float4 kq[4];
#pragma unroll
            for (int s = 0; s < 4; ++s)
                kq[s] = *(const float4*)&Ks[s * 16 + tjs][d4 * 4];
#pragma unroll
            for (int r = 0; r < 4; ++r) {
                float4 qa = *(const float4*)&Qs[tis * 4 + r][d4 * 4];
#pragma unroll
                for (int s = 0; s < 4; ++s)
                    sacc[r][s] += qa.x * kq[s].x + qa.y * kq[s].y +
                                  qa.z * kq[s].z + qa.w * kq[s].w;
            }
        }
#pragma unroll
        for (int r = 0; r < 4; ++r)
#pragma unroll
            for (int s = 0; s < 4; ++s)
                lsum[s] += __expf(sacc[r][s] * SCALE);
        __syncthreads();
    }

#pragma unroll
    for (int s = 0; s < 4; ++s)
        red[tis][s * 16 + tjs] = lsum[s];
    __syncthreads();
    if (tid < 64) {
        float t = 0.f;
#pragma unroll
        for (int ii = 0; ii < 16; ++ii) t += red[ii][tid];
        coef[(size_t)bh * Nc + j0 + tid] = 1.0f / t;
    }
}

// ---------------------------------------------------------------------------
// Kernel 3: res[b,i,h*64+d] = sum_j exp(scale*q_i.k_j) * coef_j * v[j,d]
// grid (Nc/64 i-tiles, Bc*Hc), block 256. j-tile = 32.
// S phase: rows i = tis*4+r, cols j = s*16+tjs (s in 0..1).
// PV phase: rows i = tis*4+r, cols d = tjs*4+s.
// ---------------------------------------------------------------------------
__global__ __launch_bounds__(256) void apply_kernel(
    const float* __restrict__ qws, const float* __restrict__ kws,
    const float* __restrict__ vws, const float* __restrict__ coef,
    float* __restrict__ res)
{
    __shared__ float Qs[64][68];
    __shared__ float Ks[32][68];
    __shared__ float Vs[32][68];
    __shared__ float Ps[64][36];
    const int tid = threadIdx.x;
    const int bh = blockIdx.y;
    const int i0 = blockIdx.x * 64;
    const int tjs = tid & 15;
    const int tis = tid >> 4;

    const float* qbase = qws + ((size_t)bh * Nc + i0) * DKc;
#pragma unroll
    for (int it = 0; it < 4; ++it) {
        int e = it * 256 + tid;
        int row = e >> 4, c4 = e & 15;
        *(float4*)&Qs[row][c4 * 4] = *(const float4*)&qbase[(size_t)row * DKc + c4 * 4];
    }

    float acc[4][4] = {};  // [r][s]: i = tis*4+r, d = tjs*4+s
    const float* kbase = kws + (size_t)bh * Nc * DKc;
    const float* vbase = vws + (size_t)bh * Nc * DKc;
    const float* cf    = coef + (size_t)bh * Nc;

    for (int j0 = 0; j0 < Nc; j0 += 32) {
#pragma unroll
        for (int it = 0; it < 2; ++it) {
            int e = it * 256 + tid;
            int row = e >> 4, c4 = e & 15;
            *(float4*)&Ks[row][c4 * 4] =
                *(const float4*)&kbase[(size_t)(j0 + row) * DKc + c4 * 4];
            *(float4*)&Vs[row][c4 * 4] =
                *(const float4*)&vbase[(size_t)(j0 + row) * DKc + c4 * 4];
        }
        __syncthreads();

        // S = Q K^T for this j-tile
        float sacc[4][2] = {};
#pragma unroll
        for (int d4 = 0; d4 < 16; ++d4) {
            float4 k0 = *(const float4*)&Ks[tjs][d4 * 4];
            float4 k1 = *(const float4*)&Ks[16 + tjs][d4 * 4];
#pragma unroll
            for (int r = 0; r < 4; ++r) {
                float4 qa = *(const float4*)&Qs[tis * 4 + r][d4 * 4];
                sacc[r][0] += qa.x * k0.x + qa.y * k0.y + qa.z * k0.z + qa.w * k0.w;
                sacc[r][1] += qa.x * k1.x + qa.y * k1.y + qa.z * k1.z + qa.w * k1.w;
            }
        }
        float c0 = cf[j0 + tjs];
        float c1 = cf[j0 + 16 + tjs];
#pragma unroll
        for (int r = 0; r < 4; ++r) {
            Ps[tis * 4 + r][tjs]      = __expf(sacc[r][0] * SCALE) * c0;
            Ps[tis * 4 + r][16 + tjs] = __expf(sacc[r][1] * SCALE) * c1;
        }
        __syncthreads();

        // acc += P(64x32) @ V(32x64)
#pragma unroll
        for (int j4 = 0; j4 < 8; ++j4) {
            float4 vb[4];
#pragma unroll
            for (int u = 0; u < 4; ++u)
                vb[u] = *(const float4*)&Vs[j4 * 4 + u][tjs * 4];
#pragma unroll
            for (int r = 0; r < 4; ++r) {
                float4 pa = *(const float4*)&Ps[tis * 4 + r][j4 * 4];
                acc[r][0] += pa.x * vb[0].x + pa.y * vb[1].x + pa.z * vb[2].x + pa.w * vb[3].x;
                acc[r][1] += pa.x * vb[0].y + pa.y * vb[1].y + pa.z * vb[2].y + pa.w * vb[3].y;
                acc[r][2] += pa.x * vb[0].z + pa.y * vb[1].z + pa.z * vb[2].z + pa.w * vb[3].z;
                acc[r][3] += pa.x * vb[0].w + pa.y * vb[1].w + pa.z * vb[2].w + pa.w * vb[3].w;
            }
        }
        __syncthreads();
    }

    const int b = bh >> 3, h = bh & 7;
    float* rbase = res + ((size_t)b * Nc + i0) * Cc + h * DKc;
#pragma unroll
    for (int r = 0; r < 4; ++r) {
        float4 v = {acc[r][0], acc[r][1], acc[r][2], acc[r][3]};
        *(float4*)&rbase[(size_t)(tis * 4 + r) * Cc + tjs * 4] = v;
    }
}

// ---------------------------------------------------------------------------
// Kernel 4: out[b,co,n] = sum_c res[b,n,c]*Wo[co,c] + bo[co] + x[b,co,n]
// grid (Nc/64, Cc/64, Bc), block 256.
// ---------------------------------------------------------------------------
__global__ __launch_bounds__(256) void out_kernel(
    const float* __restrict__ res, const float* __restrict__ Wo,
    const float* __restrict__ bo, const float* __restrict__ x,
    float* __restrict__ out)
{
    __shared__ float As[16][68];   // [k][n]
    __shared__ float Bs[16][68];   // [k][co]
    const int tid = threadIdx.x;
    const int b   = blockIdx.z;
    const int n0  = blockIdx.x * 64;
    const int co0 = blockIdx.y * 64;
    const int tn = tid & 15, tc = tid >> 4;
    float acc[4][4] = {};  // [r(n)][s(co)]
    const float* rbase = res + (size_t)b * Nc * Cc;

    for (int kc = 0; kc < Cc; kc += 16) {
#pragma unroll
        for (int it = 0; it < 4; ++it) {
            int e = it * 256 + tid;
            int nl = e >> 4, kk = e & 15;
            As[kk][nl] = rbase[(size_t)(n0 + nl) * Cc + kc + kk];
            Bs[kk][nl] = Wo[(size_t)(co0 + nl) * Cc + kc + kk];
        }
        __syncthreads();
#pragma unroll
        for (int kk = 0; kk < 16; ++kk) {
            float4 a  = *(const float4*)&As[kk][tn * 4];
            float4 bv = *(const float4*)&Bs[kk][tc * 4];
            float av[4] = {a.x, a.y, a.z, a.w};
            float bw[4] = {bv.x, bv.y, bv.z, bv.w};
#pragma unroll
            for (int r = 0; r < 4; ++r)
#pragma unroll
                for (int s = 0; s < 4; ++s)
                    acc[r][s] += av[r] * bw[s];
        }
        __syncthreads();
    }

    const float* xb = x   + (size_t)b * Cc * Nc;
    float*       ob = out + (size_t)b * Cc * Nc;
#pragma unroll
    for (int s = 0; s < 4; ++s) {
        int co = co0 + tc * 4 + s;
        float bos = bo[co];
        float4 xr = *(const float4*)&xb[(size_t)co * Nc + n0 + tn * 4];
        float4 v;
        v.x = acc[0][s] + bos + xr.x;
        v.y = acc[1][s] + bos + xr.y;
        v.z = acc[2][s] + bos + xr.z;
        v.w = acc[3][s] + bos + xr.w;
        *(float4*)&ob[(size_t)co * Nc + n0 + tn * 4] = v;
    }
}

// ---------------------------------------------------------------------------
extern "C" void kernel_launch(void* const* d_in, const int* in_sizes, int n_in,
                              void* d_out, int out_size, void* d_ws, size_t ws_size,
                              hipStream_t stream)
{
    const float* x  = (const float*)d_in[0];
    const float* Wp = (const float*)d_in[1];
    const float* bp = (const float*)d_in[2];
    const float* Wo = (const float*)d_in[3];
    const float* bo = (const float*)d_in[4];
    float* out = (float*)d_out;

    float* ws = (float*)d_ws;
    const size_t qkv_elems = (size_t)Bc * Hc * Nc * DKc;   // 4,194,304
    float* qws  = ws;
    float* kws  = qws + qkv_elems;
    float* vws  = kws + qkv_elems;
    float* coef = vws + qkv_elems;                         // B*H*N = 65,536
    float* res  = coef + (size_t)Bc * Hc * Nc;             // B*N*C = 4,194,304

    qkv_kernel<<<dim3(Nc / 64, O3c / 64, Bc), 256, 0, stream>>>(x, Wp, bp, qws, kws, vws);
    stats_kernel<<<dim3(Nc / 64, Bc * Hc), 256, 0, stream>>>(qws, kws, coef);
    apply_kernel<<<dim3(Nc / 64, Bc * Hc), 256, 0, stream>>>(qws, kws, vws, coef, res);
    out_kernel<<<dim3(Nc / 64, Cc / 64, Bc), 256, 0, stream>>>(res, Wo, bo, x, out);
}

// Round 2
// 345.986 us; speedup vs baseline: 4.3964x; 4.3964x over previous
//
#include <hip/hip_runtime.h>
#include <cstddef>

typedef unsigned short ushort_t;
typedef __attribute__((ext_vector_type(8))) short sh8;   // 8 x bf16 bits = 4 VGPRs
typedef __attribute__((ext_vector_type(4))) float f4;    // MFMA 16x16x32 C/D
typedef __attribute__((ext_vector_type(4))) unsigned short us4;

static constexpr int Bc = 4, Cc = 512, Nc = 2048, Hc = 8, DKc = 64, O3c = 1536;
static constexpr float SCALE = 0.125f;  // DK^-0.5

__device__ __forceinline__ unsigned short f2bf(float f) {
    union { float f; unsigned u; } v; v.f = f;
    unsigned r = v.u + 0x7FFFu + ((v.u >> 16) & 1u);  // RNE
    return (unsigned short)(r >> 16);
}

// ---------------------------------------------------------------------------
// Prep A: x[b,c,n] fp32 -> xt[b,n,c] bf16 (LDS 32x32 tile transpose)
// ---------------------------------------------------------------------------
__global__ __launch_bounds__(256) void xpose_kernel(
    const float* __restrict__ x, ushort_t* __restrict__ xt)
{
    __shared__ float t[32][33];
    const int b = blockIdx.z, n0 = blockIdx.x * 32, c0 = blockIdx.y * 32;
    const int tx = threadIdx.x & 31, ty = threadIdx.x >> 5;
    const float* xb = x + (size_t)b * Cc * Nc;
#pragma unroll
    for (int r = 0; r < 4; ++r)
        t[ty + r * 8][tx] = xb[(size_t)(c0 + ty + r * 8) * Nc + n0 + tx];
    __syncthreads();
    ushort_t* xtb = xt + (size_t)b * Nc * Cc;
#pragma unroll
    for (int r = 0; r < 4; ++r)
        xtb[(size_t)(n0 + ty + r * 8) * Cc + c0 + tx] = f2bf(t[tx][ty + r * 8]);
}

// ---------------------------------------------------------------------------
// Prep B: fp32 -> bf16 bulk convert (vectorized), n4 = count/4
// ---------------------------------------------------------------------------
__global__ __launch_bounds__(256) void cvt_kernel(
    const float* __restrict__ s, ushort_t* __restrict__ d, int n4)
{
    int i = blockIdx.x * 256 + threadIdx.x;
    if (i < n4) {
        float4 v = ((const float4*)s)[i];
        us4 o = { f2bf(v.x), f2bf(v.y), f2bf(v.z), f2bf(v.w) };
        ((us4*)d)[i] = o;
    }
}

// ---------------------------------------------------------------------------
// Kernel 1: qkv projection via MFMA.  C[m=token, o] = xt @ Wp^T + bp
// Tile 128x128, 4 waves each 64x64 (4x4 16-frags). Direct-global frag loads.
// Per-wave o-range is one 64-block => uniform (head, field); scatter into
// q[bh,n,d], k[bh,n,d], vT[bh,d,n] (v transposed for PV B-operand).
// ---------------------------------------------------------------------------
__global__ __launch_bounds__(256) void qkv_kernel(
    const ushort_t* __restrict__ xt, const ushort_t* __restrict__ Wpb,
    const float* __restrict__ bp,
    ushort_t* __restrict__ q, ushort_t* __restrict__ k, ushort_t* __restrict__ vT)
{
    const int tid = threadIdx.x;
    const int wave = tid >> 6, lane = tid & 63, quad = lane >> 4, l15 = lane & 15;
    const int b = blockIdx.z;
    const int m0 = blockIdx.y * 128 + (wave & 1) * 64;   // token
    const int o0 = blockIdx.x * 128 + (wave >> 1) * 64;  // qkv feature
    const ushort_t* A  = xt  + ((size_t)b * Nc + m0) * Cc;
    const ushort_t* Bp = Wpb + (size_t)o0 * Cc;

    f4 acc[4][4];
#pragma unroll
    for (int i = 0; i < 4; ++i)
#pragma unroll
        for (int j = 0; j < 4; ++j) acc[i][j] = (f4)0.f;

    for (int kk = 0; kk < Cc; kk += 32) {
        sh8 a[4], bb[4];
#pragma unroll
        for (int mi = 0; mi < 4; ++mi)
            a[mi] = *(const sh8*)&A[(size_t)(mi * 16 + l15) * Cc + kk + quad * 8];
#pragma unroll
        for (int ni = 0; ni < 4; ++ni)
            bb[ni] = *(const sh8*)&Bp[(size_t)(ni * 16 + l15) * Cc + kk + quad * 8];
#pragma unroll
        for (int mi = 0; mi < 4; ++mi)
#pragma unroll
            for (int ni = 0; ni < 4; ++ni)
                acc[mi][ni] = __builtin_amdgcn_mfma_f32_16x16x32_bf16(
                    a[mi], bb[ni], acc[mi][ni], 0, 0, 0);
    }

    const int f  = (o0 >> 6) % 3;   // 0=q 1=k 2=v (wave-uniform)
    const int h  = o0 / 192;
    const int bh = b * Hc + h;
#pragma unroll
    for (int ni = 0; ni < 4; ++ni) {
        const int o = o0 + ni * 16 + l15;
        const int d = o & 63;
        const float bias = bp[o];
        if (f == 2) {
            ushort_t* dst = vT + ((size_t)bh * DKc + d) * Nc + m0;
#pragma unroll
            for (int mi = 0; mi < 4; ++mi) {
                us4 pk = { f2bf(acc[mi][ni][0] + bias), f2bf(acc[mi][ni][1] + bias),
                           f2bf(acc[mi][ni][2] + bias), f2bf(acc[mi][ni][3] + bias) };
                *(us4*)&dst[mi * 16 + quad * 4] = pk;
            }
        } else {
            ushort_t* dst = (f == 0 ? q : k) + ((size_t)bh * Nc + m0) * DKc + d;
#pragma unroll
            for (int mi = 0; mi < 4; ++mi)
#pragma unroll
                for (int r = 0; r < 4; ++r)
                    dst[(size_t)(mi * 16 + quad * 4 + r) * DKc] =
                        f2bf(acc[mi][ni][r] + bias);
        }
    }
}

// ---------------------------------------------------------------------------
// Kernel 2: column sums. coef[bh,j] = 1 / sum_i exp(scale * q_i . k_j)
// A = K (m=j), B = Q (n=i): C = S^T tile; exp + accumulate over columns,
// shuffle-reduce across the 16 column-lanes at the end. No LDS, no barriers.
// ---------------------------------------------------------------------------
__global__ __launch_bounds__(256) void stats_kernel(
    const ushort_t* __restrict__ q, const ushort_t* __restrict__ k,
    float* __restrict__ coef)
{
    const int tid = threadIdx.x;
    const int wave = tid >> 6, lane = tid & 63, quad = lane >> 4, l15 = lane & 15;
    const int bh = blockIdx.y;
    const int j0 = blockIdx.x * 128 + wave * 32;
    const ushort_t* K = k + ((size_t)bh * Nc + j0) * DKc;
    const ushort_t* Q = q + (size_t)bh * Nc * DKc;

    sh8 aK[2][2];
#pragma unroll
    for (int mi = 0; mi < 2; ++mi)
#pragma unroll
        for (int kk = 0; kk < 2; ++kk)
            aK[mi][kk] = *(const sh8*)&K[(size_t)(mi * 16 + l15) * DKc + kk * 32 + quad * 8];

    float lsum[2][4] = {};
    for (int i0 = 0; i0 < Nc; i0 += 64) {
        sh8 bQ[4][2];
#pragma unroll
        for (int ni = 0; ni < 4; ++ni)
#pragma unroll
            for (int kk = 0; kk < 2; ++kk)
                bQ[ni][kk] = *(const sh8*)&Q[(size_t)(i0 + ni * 16 + l15) * DKc + kk * 32 + quad * 8];
#pragma unroll
        for (int mi = 0; mi < 2; ++mi)
#pragma unroll
            for (int ni = 0; ni < 4; ++ni) {
                f4 s = (f4)0.f;
                s = __builtin_amdgcn_mfma_f32_16x16x32_bf16(aK[mi][0], bQ[ni][0], s, 0, 0, 0);
                s = __builtin_amdgcn_mfma_f32_16x16x32_bf16(aK[mi][1], bQ[ni][1], s, 0, 0, 0);
#pragma unroll
                for (int r = 0; r < 4; ++r)
                    lsum[mi][r] += __expf(s[r] * SCALE);
            }
    }
#pragma unroll
    for (int mi = 0; mi < 2; ++mi)
#pragma unroll
        for (int r = 0; r < 4; ++r) {
            float v = lsum[mi][r];
            v += __shfl_xor(v, 1); v += __shfl_xor(v, 2);
            v += __shfl_xor(v, 4); v += __shfl_xor(v, 8);
            if (l15 == 0)
                coef[(size_t)bh * Nc + j0 + mi * 16 + quad * 4 + r] = 1.0f / v;
        }
}

// ---------------------------------------------------------------------------
// Kernel 3: res[b, i, h*64+d] = sum_j exp(scale*q_i.k_j)*coef_j * v[j,d]
// Per wave: 32 q-rows, full d=64. S via MFMA -> P (bf16) -> per-wave LDS
// round-trip (C-layout -> A-layout) -> PV MFMA. No __syncthreads.
// ---------------------------------------------------------------------------
__global__ __launch_bounds__(256) void apply_kernel(
    const ushort_t* __restrict__ q, const ushort_t* __restrict__ k,
    const ushort_t* __restrict__ vT, const float* __restrict__ coef,
    ushort_t* __restrict__ res)
{
    __shared__ ushort_t P[4][32][72];  // per-wave, row-padded +8
    const int tid = threadIdx.x;
    const int wave = tid >> 6, lane = tid & 63, quad = lane >> 4, l15 = lane & 15;
    const int bh = blockIdx.y;
    const int b = bh >> 3, h = bh & 7;
    const int i0 = blockIdx.x * 128 + wave * 32;
    const ushort_t* Q = q  + ((size_t)bh * Nc + i0) * DKc;
    const ushort_t* K = k  + (size_t)bh * Nc * DKc;
    const ushort_t* V = vT + (size_t)bh * DKc * Nc;
    const float*   cf = coef + (size_t)bh * Nc;

    sh8 aQ[2][2];
#pragma unroll
    for (int mi = 0; mi < 2; ++mi)
#pragma unroll
        for (int kk = 0; kk < 2; ++kk)
            aQ[mi][kk] = *(const sh8*)&Q[(size_t)(mi * 16 + l15) * DKc + kk * 32 + quad * 8];

    f4 acc[2][4];
#pragma unroll
    for (int i = 0; i < 2; ++i)
#pragma unroll
        for (int j = 0; j < 4; ++j) acc[i][j] = (f4)0.f;

    for (int j0 = 0; j0 < Nc; j0 += 64) {
        // S = Q K^T (32 x 64)
        sh8 bK[4][2];
#pragma unroll
        for (int nj = 0; nj < 4; ++nj)
#pragma unroll
            for (int kk = 0; kk < 2; ++kk)
                bK[nj][kk] = *(const sh8*)&K[(size_t)(j0 + nj * 16 + l15) * DKc + kk * 32 + quad * 8];
#pragma unroll
        for (int mi = 0; mi < 2; ++mi)
#pragma unroll
            for (int nj = 0; nj < 4; ++nj) {
                f4 s = (f4)0.f;
                s = __builtin_amdgcn_mfma_f32_16x16x32_bf16(aQ[mi][0], bK[nj][0], s, 0, 0, 0);
                s = __builtin_amdgcn_mfma_f32_16x16x32_bf16(aQ[mi][1], bK[nj][1], s, 0, 0, 0);
                const float c = cf[j0 + nj * 16 + l15];
#pragma unroll
                for (int r = 0; r < 4; ++r)
                    P[wave][mi * 16 + quad * 4 + r][nj * 16 + l15] =
                        f2bf(__expf(s[r] * SCALE) * c);
            }
        // P: C-layout -> A-layout via per-wave LDS (compiler inserts lgkmcnt)
        sh8 aP[2][2];
#pragma unroll
        for (int mi = 0; mi < 2; ++mi)
#pragma unroll
            for (int kk = 0; kk < 2; ++kk)
                aP[mi][kk] = *(const sh8*)&P[wave][mi * 16 + l15][kk * 32 + quad * 8];
        // PV: B = V^T rows (d fixed per lane, j contiguous)
        sh8 bV[4][2];
#pragma unroll
        for (int ni = 0; ni < 4; ++ni)
#pragma unroll
            for (int kk = 0; kk < 2; ++kk)
                bV[ni][kk] = *(const sh8*)&V[(size_t)(ni * 16 + l15) * Nc + j0 + kk * 32 + quad * 8];
#pragma unroll
        for (int mi = 0; mi < 2; ++mi)
#pragma unroll
            for (int ni = 0; ni < 4; ++ni) {
                acc[mi][ni] = __builtin_amdgcn_mfma_f32_16x16x32_bf16(
                    aP[mi][0], bV[ni][0], acc[mi][ni], 0, 0, 0);
                acc[mi][ni] = __builtin_amdgcn_mfma_f32_16x16x32_bf16(
                    aP[mi][1], bV[ni][1], acc[mi][ni], 0, 0, 0);
            }
    }

    ushort_t* rb = res + ((size_t)b * Nc + i0) * Cc + h * DKc;
#pragma unroll
    for (int mi = 0; mi < 2; ++mi)
#pragma unroll
        for (int ni = 0; ni < 4; ++ni)
#pragma unroll
            for (int r = 0; r < 4; ++r)
                rb[(size_t)(mi * 16 + quad * 4 + r) * Cc + ni * 16 + l15] =
                    f2bf(acc[mi][ni][r]);
}

// ---------------------------------------------------------------------------
// Kernel 4: out[b,co,n] = res @ Wo^T + bo + x   (epilogue does the transpose:
// C rows = 4 consecutive tokens -> float4 store along n)
// ---------------------------------------------------------------------------
__global__ __launch_bounds__(256) void out_kernel(
    const ushort_t* __restrict__ res, const ushort_t* __restrict__ Wob,
    const float* __restrict__ bo, const float* __restrict__ x,
    float* __restrict__ out)
{
    const int tid = threadIdx.x;
    const int wave = tid >> 6, lane = tid & 63, quad = lane >> 4, l15 = lane & 15;
    const int m0  = blockIdx.x * 128 + (wave & 1) * 64;   // global token (b*N+n)
    const int co0 = blockIdx.y * 128 + (wave >> 1) * 64;
    const ushort_t* A  = res + (size_t)m0 * Cc;
    const ushort_t* Bw = Wob + (size_t)co0 * Cc;

    f4 acc[4][4];
#pragma unroll
    for (int i = 0; i < 4; ++i)
#pragma unroll
        for (int j = 0; j < 4; ++j) acc[i][j] = (f4)0.f;

    for (int kk = 0; kk < Cc; kk += 32) {
        sh8 a[4], bb[4];
#pragma unroll
        for (int mi = 0; mi < 4; ++mi)
            a[mi] = *(const sh8*)&A[(size_t)(mi * 16 + l15) * Cc + kk + quad * 8];
#pragma unroll
        for (int ni = 0; ni < 4; ++ni)
            bb[ni] = *(const sh8*)&Bw[(size_t)(ni * 16 + l15) * Cc + kk + quad * 8];
#pragma unroll
        for (int mi = 0; mi < 4; ++mi)
#pragma unroll
            for (int ni = 0; ni < 4; ++ni)
                acc[mi][ni] = __builtin_amdgcn_mfma_f32_16x16x32_bf16(
                    a[mi], bb[ni], acc[mi][ni], 0, 0, 0);
    }

    const int b = m0 >> 11;           // token / 2048
    const int n_base = m0 & 2047;
#pragma unroll
    for (int ni = 0; ni < 4; ++ni) {
        const int co = co0 + ni * 16 + l15;
        const float bias = bo[co];
#pragma unroll
        for (int mi = 0; mi < 4; ++mi) {
            const int n = n_base + mi * 16 + quad * 4;
            const size_t idx = ((size_t)b * Cc + co) * Nc + n;
            float4 xr = *(const float4*)&x[idx];
            float4 o;
            o.x = acc[mi][ni][0] + bias + xr.x;
            o.y = acc[mi][ni][1] + bias + xr.y;
            o.z = acc[mi][ni][2] + bias + xr.z;
            o.w = acc[mi][ni][3] + bias + xr.w;
            *(float4*)&out[idx] = o;
        }
    }
}

// ---------------------------------------------------------------------------
extern "C" void kernel_launch(void* const* d_in, const int* in_sizes, int n_in,
                              void* d_out, int out_size, void* d_ws, size_t ws_size,
                              hipStream_t stream)
{
    const float* x  = (const float*)d_in[0];
    const float* Wp = (const float*)d_in[1];
    const float* bp = (const float*)d_in[2];
    const float* Wo = (const float*)d_in[3];
    const float* bo = (const float*)d_in[4];
    float* out = (float*)d_out;

    // workspace layout: coef (fp32) first for alignment, then bf16 arrays
    float* coef = (float*)d_ws;                                  // B*H*N
    ushort_t* ws = (ushort_t*)(coef + (size_t)Bc * Hc * Nc);
    const size_t nE = (size_t)Bc * Nc * Cc;      // 4,194,304 (== B*H*N*DK)
    ushort_t* xt  = ws;
    ushort_t* Wpb = xt  + nE;
    ushort_t* Wob = Wpb + (size_t)O3c * Cc;
    ushort_t* qw  = Wob + (size_t)Cc * Cc;
    ushort_t* kw  = qw + nE;
    ushort_t* vT  = kw + nE;
    ushort_t* res = vT + nE;

    xpose_kernel<<<dim3(Nc / 32, Cc / 32, Bc), 256, 0, stream>>>(x, xt);
    cvt_kernel<<<dim3((O3c * Cc / 4 + 255) / 256), 256, 0, stream>>>(Wp, Wpb, O3c * Cc / 4);
    cvt_kernel<<<dim3((Cc * Cc / 4 + 255) / 256), 256, 0, stream>>>(Wo, Wob, Cc * Cc / 4);
    qkv_kernel<<<dim3(O3c / 128, Nc / 128, Bc), 256, 0, stream>>>(xt, Wpb, bp, qw, kw, vT);
    stats_kernel<<<dim3(Nc / 128, Bc * Hc), 256, 0, stream>>>(qw, kw, coef);
    apply_kernel<<<dim3(Nc / 128, Bc * Hc), 256, 0, stream>>>(qw, kw, vT, coef, res);
    out_kernel<<<dim3(Bc * Nc / 128, Cc / 128), 256, 0, stream>>>(res, Wob, bo, x, out);
}